// Round 12
// baseline (741.458 us; speedup 1.0000x reference)
//
#include <hip/hip_runtime.h>

// ---------------------------------------------------------------------------
// RNN-T Joint Network, MI355X (gfx950)
//   f  = enc  @ W_enc^T   : [2048 x 640]
//   g  = pred @ W_pred^T  : [ 512 x 640]
//   out[b,t,u,v] = sum_j tanh(f[bt,j] + g[bu,j]) * W_out[v,j] + b_out[v]
// R12 = R10 (8-wave block, acc 64, 2 blocks/CU -- occupancy 45% measured)
// with its two execution bugs fixed:
//   (1) cached scalar stores (R10's nontemporal scalar stores caused x4.7
//       write amplification: WRITE_SIZE 2.47 GB),
//   (2) A-region stride 528 f16 = 66 quads = 2 mod 8 (R10's 520 = 1 mod 8
//       collided write quads: conflicts 1.31e7 -> predicted ~0).
// Carries: pre-tiled Wh (coalesced gll + identity conflict-free B ds_read),
// f/g loads before glls, setprio, XCD-chunked swizzle.
// ---------------------------------------------------------------------------

typedef _Float16 f16x8 __attribute__((ext_vector_type(8)));
typedef float    f32x4 __attribute__((ext_vector_type(4)));

__device__ __forceinline__ float fast_tanh(float x) {
    float e = __builtin_amdgcn_exp2f(x * 2.88539008177792681472f);
    return 1.0f - 2.0f * __builtin_amdgcn_rcpf(e + 1.0f);
}

__device__ __forceinline__ void gll16(const void* g, void* l) {
    __builtin_amdgcn_global_load_lds(
        (const __attribute__((address_space(1))) void*)g,
        (__attribute__((address_space(3))) void*)l, 16, 0, 0);
}

// ---------------------------------------------------------------------------
// Kernel 1: fg GEMM (fp32, exact). W staged transposed -> broadcast reads.
// ---------------------------------------------------------------------------
__global__ __launch_bounds__(256) void fg_kernel(
    const float* __restrict__ enc, const float* __restrict__ pred,
    const float* __restrict__ Wenc, const float* __restrict__ Wpred,
    float* __restrict__ fg)
{
    __shared__ float As[64][36];
    __shared__ float WsT[32][68];

    const int bid = blockIdx.x;
    const int mt = bid / 10;
    const int nt = bid % 10;
    const int m0 = mt * 64;
    const int n0 = nt * 64;

    const float* Aptr;
    const float* Wptr;
    if (m0 < 2048) { Aptr = enc  + (size_t)m0 * 512;          Wptr = Wenc; }
    else           { Aptr = pred + (size_t)(m0 - 2048) * 512; Wptr = Wpred; }

    const int t  = threadIdx.x;
    const int ty = t >> 4;
    const int tx = t & 15;
    const int lr = t >> 2;
    const int lc = (t & 3) * 8;
    const int lane6 = t & 63;
    const int w8    = (t >> 6) * 8;

    float acc[4][4];
#pragma unroll
    for (int i = 0; i < 4; ++i)
#pragma unroll
        for (int j = 0; j < 4; ++j) acc[i][j] = 0.0f;

    for (int k0 = 0; k0 < 512; k0 += 32) {
        __syncthreads();
        {
            const float* sa = Aptr + (size_t)lr * 512 + k0 + lc;
            f32x4 a0 = *(const f32x4*)(sa);
            f32x4 a1 = *(const f32x4*)(sa + 4);
            *(f32x4*)&As[lr][lc]     = a0;
            *(f32x4*)&As[lr][lc + 4] = a1;
            const float* sw = Wptr + (size_t)(n0 + lane6) * 512 + k0 + w8;
            f32x4 w0 = *(const f32x4*)(sw);
            f32x4 w1 = *(const f32x4*)(sw + 4);
#pragma unroll
            for (int j = 0; j < 4; ++j) {
                WsT[w8 + j][lane6]     = w0[j];
                WsT[w8 + 4 + j][lane6] = w1[j];
            }
        }
        __syncthreads();
#pragma unroll
        for (int kk = 0; kk < 32; ++kk) {
            float av[4], bv[4];
#pragma unroll
            for (int i = 0; i < 4; ++i) av[i] = As[ty * 4 + i][kk];
#pragma unroll
            for (int j = 0; j < 4; ++j) bv[j] = WsT[kk][tx * 4 + j];
#pragma unroll
            for (int i = 0; i < 4; ++i)
#pragma unroll
                for (int j = 0; j < 4; ++j)
                    acc[i][j] = fmaf(av[i], bv[j], acc[i][j]);
        }
    }

#pragma unroll
    for (int i = 0; i < 4; ++i) {
        f32x4 v = { acc[i][0], acc[i][1], acc[i][2], acc[i][3] };
        *(f32x4*)&fg[(size_t)(m0 + ty * 4 + i) * 640 + n0 + tx * 4] = v;
    }
}

// ---------------------------------------------------------------------------
// Kernel 2: W_out fp32 [1024][640] -> fp16, TILED to the joint kernel's LDS
// image: elem offset = seg*10240 + kc*512 + L*8 + j, seg = n>>4, kc = k>>5,
// L = (n&15) + 16*((k>>3)&3).  64-lane gll at base + lane*8 reads one
// contiguous 1KB tile; slot L holds the (row, k-chunk) the MFMA B-fragment
// wants at lane L  ->  coalesced global AND zero-conflict identity ds_read.
// ---------------------------------------------------------------------------
__global__ __launch_bounds__(256) void wconv_kernel(
    const float* __restrict__ W, _Float16* __restrict__ Wh)
{
    const int tid = blockIdx.x * 256 + threadIdx.x;    // 81920 = 1024*80
    const int n   = tid / 80;
    const int c   = tid % 80;                          // k-chunk of 8
    f32x4 a = *(const f32x4*)(W + (size_t)n * 640 + c * 8);
    f32x4 b = *(const f32x4*)(W + (size_t)n * 640 + c * 8 + 4);
    f16x8 h;
#pragma unroll
    for (int j = 0; j < 4; ++j) { h[j] = (_Float16)a[j]; h[4 + j] = (_Float16)b[j]; }
    const int seg = n >> 4;
    const int kc  = c >> 2;
    const int L   = (n & 15) + 16 * (c & 3);
    *(f16x8*)(Wh + (size_t)seg * 10240 + kc * 512 + L * 8) = h;
}

// ---------------------------------------------------------------------------
// Kernel 3: fused tanh + big GEMM.  BM=64, BN=512, BK=32, 512 thr = 8 waves,
// wave tile 64m x 64n (4x4 16x16 frags, 64 AGPR). launch_bounds(512,4) ->
// <=128 regs/wave (R10 measured VGPR=64) -> 2 blocks/CU (occupancy 45%):
// one block's store burst overlaps the other's K-loop; 4 waves/SIMD hiding.
// B: tiled-gll -> identity LDS (zero conflict, coalesced).  A: region
// stride 528 f16 (66 quads = 2 mod 8): write quads (2q+r)%8 and read quads
// (2lk+row)%8 distinct per 8-lane group -> zero conflicts (enumerated).
// Per-iter: f/g loads(next) -> gll B(next) -> frag reads(cur) ->
//   tanh(next) -> MFMA(cur, setprio) -> ds_write A(next) -> sync.
// A staged by threads t<256 (4 thr/row, 8 elems each).
// ---------------------------------------------------------------------------
__global__ __launch_bounds__(512, 4) void joint_kernel(
    const float* __restrict__ fg, const _Float16* __restrict__ Wh,
    const float* __restrict__ bias, float* __restrict__ out)
{
    __shared__ _Float16 Ash0[4 * 528];     // 4224 B
    __shared__ _Float16 Ash1[4 * 528];
    __shared__ _Float16 Bsh0[512 * 32];    // 32 KB
    __shared__ _Float16 Bsh1[512 * 32];

    const int bid = blockIdx.x;            // 4096
    const int pp  = bid >> 1;              // 2048 m-tiles
    const int mt  = (pp & 7) * 256 + (pp >> 3);   // XCD-chunked (bijective)
    const int nt  = bid & 1;
    const int m0  = mt << 6;
    const int n0s = nt * 32;               // first B segment (16 rows each)

    const int t    = threadIdx.x;
    const int lane = t & 63;
    const int wid  = t >> 6;               // 0..7 = wn (64-col slice)
    const int wn   = wid;
    const int lr   = lane & 15;
    const int lk   = lane >> 4;

    // stage-A mapping (threads t<256): 4 threads per row, 8 k each
    const int r  = (t & 255) >> 2;         // 0..63
    const int q  = t & 3;
    const bool astage = (t < 256);
    const int m  = m0 + r;
    const float* grow = fg + (size_t)(2048 + ((m >> 14) << 6) + (m & 63)) * 640;
    const float* frow = fg + (size_t)mt * 640;   // one f-row per block

    // ---- loop-invariant LDS offsets (f16 elems) ----
    int aoff[4];
#pragma unroll
    for (int mf = 0; mf < 4; ++mf)
        aoff[mf] = lk * 528 + (mf * 16 + lr) * 8;
    int boff[4];
#pragma unroll
    for (int nf = 0; nf < 4; ++nf)
        boff[nf] = (wn * 4 + nf) * 512 + lane * 8;   // identity: zero conflict
    const int awoff = q * 528 + r * 8;

    // gll: wave stages 4 segments; lane-l source = tile base + l*8 (1KB cont.)
    const _Float16* gbase = Wh + (size_t)(n0s + wid * 4) * 10240 + lane * 8;
    int gdst[4];
#pragma unroll
    for (int i = 0; i < 4; ++i)
        gdst[i] = (wid * 4 + i) * 512;

    f32x4 acc[4][4];
#pragma unroll
    for (int i = 0; i < 4; ++i)
#pragma unroll
        for (int j = 0; j < 4; ++j) acc[i][j] = (f32x4){0.f, 0.f, 0.f, 0.f};

    // ---- prologue: stage k-range 0 into Ash0/Bsh0 ----
    {
#pragma unroll
        for (int i = 0; i < 4; ++i)
            gll16(gbase + (size_t)i * 10240, &Bsh0[gdst[i]]);
        if (astage) {
            f32x4 fv0 = *(const f32x4*)(frow + q * 8);
            f32x4 fv1 = *(const f32x4*)(frow + q * 8 + 4);
            f32x4 gv0 = *(const f32x4*)(grow + q * 8);
            f32x4 gv1 = *(const f32x4*)(grow + q * 8 + 4);
            f16x8 h;
#pragma unroll
            for (int j = 0; j < 4; ++j) {
                h[j]     = (_Float16)fast_tanh(fv0[j] + gv0[j]);
                h[4 + j] = (_Float16)fast_tanh(fv1[j] + gv1[j]);
            }
            *(f16x8*)&Ash0[awoff] = h;
        }
        __syncthreads();
    }

#define JITER_FULL(K0, CA, CB, NA, NB)                                         \
    {                                                                          \
        const int kn_ = (K0) + 32;                                             \
        /* f/g loads first; tanh consumes them before MFMA (short live) */     \
        f32x4 fv0_, fv1_, gv0_, gv1_;                                          \
        if (astage) {                                                          \
            fv0_ = *(const f32x4*)(frow + kn_ + q * 8);                        \
            fv1_ = *(const f32x4*)(frow + kn_ + q * 8 + 4);                    \
            gv0_ = *(const f32x4*)(grow + kn_ + q * 8);                        \
            gv1_ = *(const f32x4*)(grow + kn_ + q * 8 + 4);                    \
        }                                                                      \
        _Pragma("unroll")                                                      \
        for (int i = 0; i < 4; ++i)                                            \
            gll16(gbase + (size_t)i * 10240 + kn_ * 16, &NB[gdst[i]]);         \
        f16x8 af[4], bf[4];                                                    \
        _Pragma("unroll")                                                      \
        for (int mf = 0; mf < 4; ++mf)                                         \
            af[mf] = *(const f16x8*)&CA[aoff[mf]];                             \
        _Pragma("unroll")                                                      \
        for (int nf = 0; nf < 4; ++nf)                                         \
            bf[nf] = *(const f16x8*)&CB[boff[nf]];                             \
        f16x8 h_;                                                              \
        if (astage) {                                                          \
            _Pragma("unroll")                                                  \
            for (int j = 0; j < 4; ++j) {                                      \
                h_[j]     = (_Float16)fast_tanh(fv0_[j] + gv0_[j]);            \
                h_[4 + j] = (_Float16)fast_tanh(fv1_[j] + gv1_[j]);            \
            }                                                                  \
        }                                                                      \
        __builtin_amdgcn_s_setprio(1);                                         \
        _Pragma("unroll")                                                      \
        for (int mf = 0; mf < 4; ++mf)                                         \
            _Pragma("unroll")                                                  \
            for (int nf = 0; nf < 4; ++nf)                                     \
                acc[mf][nf] = __builtin_amdgcn_mfma_f32_16x16x32_f16(          \
                    af[mf], bf[nf], acc[mf][nf], 0, 0, 0);                     \
        __builtin_amdgcn_s_setprio(0);                                         \
        if (astage)                                                            \
            *(f16x8*)&NA[awoff] = h_;                                          \
        __syncthreads();                                                       \
    }

#define JITER_LAST(CA, CB)                                                     \
    {                                                                          \
        f16x8 af[4], bf[4];                                                    \
        _Pragma("unroll")                                                      \
        for (int mf = 0; mf < 4; ++mf)                                         \
            af[mf] = *(const f16x8*)&CA[aoff[mf]];                             \
        _Pragma("unroll")                                                      \
        for (int nf = 0; nf < 4; ++nf)                                         \
            bf[nf] = *(const f16x8*)&CB[boff[nf]];                             \
        __builtin_amdgcn_s_setprio(1);                                         \
        _Pragma("unroll")                                                      \
        for (int mf = 0; mf < 4; ++mf)                                         \
            _Pragma("unroll")                                                  \
            for (int nf = 0; nf < 4; ++nf)                                     \
                acc[mf][nf] = __builtin_amdgcn_mfma_f32_16x16x32_f16(          \
                    af[mf], bf[nf], acc[mf][nf], 0, 0, 0);                     \
        __builtin_amdgcn_s_setprio(0);                                         \
    }

    for (int kc = 0; kc < 18; kc += 2) {
        JITER_FULL(kc * 32,      Ash0, Bsh0, Ash1, Bsh1);
        JITER_FULL(kc * 32 + 32, Ash1, Bsh1, Ash0, Bsh0);
    }
    JITER_FULL(576, Ash0, Bsh0, Ash1, Bsh1);   // computes k=576, stages 608
    JITER_LAST(Ash1, Bsh1);                    // computes k=608

#undef JITER_FULL
#undef JITER_LAST

    // ---- epilogue: + bias, cached fp32 stores (exact 524 MB total) ----
    float bv[4];
#pragma unroll
    for (int nf = 0; nf < 4; ++nf)
        bv[nf] = bias[nt * 512 + wn * 64 + nf * 16 + lr];

#pragma unroll
    for (int mf = 0; mf < 4; ++mf) {
#pragma unroll
        for (int rr = 0; rr < 4; ++rr) {
            const int row = m0 + mf * 16 + lk * 4 + rr;
            float* orow = out + (size_t)row * 1024 + nt * 512 + wn * 64;
#pragma unroll
            for (int nf = 0; nf < 4; ++nf)
                orow[nf * 16 + lr] = acc[mf][nf][rr] + bv[nf];
        }
    }
}

// ---------------------------------------------------------------------------
extern "C" void kernel_launch(void* const* d_in, const int* in_sizes, int n_in,
                              void* d_out, int out_size, void* d_ws, size_t ws_size,
                              hipStream_t stream) {
    const float* enc   = (const float*)d_in[0];   // [8,256,512]
    const float* pred  = (const float*)d_in[1];   // [8,64,512]
    const float* Wenc  = (const float*)d_in[2];   // [640,512]
    const float* Wpred = (const float*)d_in[3];   // [640,512]
    const float* Wout  = (const float*)d_in[4];   // [1024,640]
    const float* bout  = (const float*)d_in[5];   // [1024]

    float*     fg = (float*)d_ws;                              // 2560*640 fp32
    _Float16*  Wh = (_Float16*)((char*)d_ws + 2560 * 640 * 4); // tiled 1.25MB

    fg_kernel<<<400, 256, 0, stream>>>(enc, pred, Wenc, Wpred, fg);
    wconv_kernel<<<320, 256, 0, stream>>>(Wout, Wh);
    joint_kernel<<<4096, 512, 0, stream>>>(fg, Wh, bout, (float*)d_out);
}

// Round 13
// 352.574 us; speedup vs baseline: 2.1030x; 2.1030x over previous
//
#include <hip/hip_runtime.h>

// ---------------------------------------------------------------------------
// RNN-T Joint Network, MI355X (gfx950)
//   f  = enc  @ W_enc^T   : [2048 x 640]
//   g  = pred @ W_pred^T  : [ 512 x 640]
//   out[b,t,u,v] = sum_j tanh(f[bt,j] + g[bu,j]) * W_out[v,j] + b_out[v]
// R13: two-N-pass K-loop with interleaved C-stores.
//   Block BM=128 x BN=512, 512 thr = 8 waves (2m x 4n). Per pass: cols 256,
//   wave tile 64m x 64n, BK=64 (10 iters/pass -> barrier count ~= R9).
//   Pass-1 acc0 stores (128 KB) are interleaved into pass-2's iterations
//   (8 dwords/thread/iter) -> half the epilogue burst hides under compute.
//   launch_bounds(512,2): NO forced reg cap (R10/R12 lesson: cap 128 ->
//   silent scratch spill -> WRITE_SIZE x4.7). acc0+acc1 = 128 AGPR.
//   A: 8 regions, stride 1040 f16 (130 quads = 2 mod 8): write quads
//     (2q+r)%8, read quads (2lk+lr)%8 distinct per 8-lane group (zero conf).
//   B: pre-tiled Wh -> coalesced gll + identity zero-conflict ds_read.
// ---------------------------------------------------------------------------

typedef _Float16 f16x8 __attribute__((ext_vector_type(8)));
typedef float    f32x4 __attribute__((ext_vector_type(4)));

__device__ __forceinline__ float fast_tanh(float x) {
    float e = __builtin_amdgcn_exp2f(x * 2.88539008177792681472f);
    return 1.0f - 2.0f * __builtin_amdgcn_rcpf(e + 1.0f);
}

__device__ __forceinline__ void gll16(const void* g, void* l) {
    __builtin_amdgcn_global_load_lds(
        (const __attribute__((address_space(1))) void*)g,
        (__attribute__((address_space(3))) void*)l, 16, 0, 0);
}

// ---------------------------------------------------------------------------
// Kernel 1: fg GEMM (fp32, exact). W staged transposed -> broadcast reads.
// ---------------------------------------------------------------------------
__global__ __launch_bounds__(256) void fg_kernel(
    const float* __restrict__ enc, const float* __restrict__ pred,
    const float* __restrict__ Wenc, const float* __restrict__ Wpred,
    float* __restrict__ fg)
{
    __shared__ float As[64][36];
    __shared__ float WsT[32][68];

    const int bid = blockIdx.x;
    const int mt = bid / 10;
    const int nt = bid % 10;
    const int m0 = mt * 64;
    const int n0 = nt * 64;

    const float* Aptr;
    const float* Wptr;
    if (m0 < 2048) { Aptr = enc  + (size_t)m0 * 512;          Wptr = Wenc; }
    else           { Aptr = pred + (size_t)(m0 - 2048) * 512; Wptr = Wpred; }

    const int t  = threadIdx.x;
    const int ty = t >> 4;
    const int tx = t & 15;
    const int lr = t >> 2;
    const int lc = (t & 3) * 8;
    const int lane6 = t & 63;
    const int w8    = (t >> 6) * 8;

    float acc[4][4];
#pragma unroll
    for (int i = 0; i < 4; ++i)
#pragma unroll
        for (int j = 0; j < 4; ++j) acc[i][j] = 0.0f;

    for (int k0 = 0; k0 < 512; k0 += 32) {
        __syncthreads();
        {
            const float* sa = Aptr + (size_t)lr * 512 + k0 + lc;
            f32x4 a0 = *(const f32x4*)(sa);
            f32x4 a1 = *(const f32x4*)(sa + 4);
            *(f32x4*)&As[lr][lc]     = a0;
            *(f32x4*)&As[lr][lc + 4] = a1;
            const float* sw = Wptr + (size_t)(n0 + lane6) * 512 + k0 + w8;
            f32x4 w0 = *(const f32x4*)(sw);
            f32x4 w1 = *(const f32x4*)(sw + 4);
#pragma unroll
            for (int j = 0; j < 4; ++j) {
                WsT[w8 + j][lane6]     = w0[j];
                WsT[w8 + 4 + j][lane6] = w1[j];
            }
        }
        __syncthreads();
#pragma unroll
        for (int kk = 0; kk < 32; ++kk) {
            float av[4], bv[4];
#pragma unroll
            for (int i = 0; i < 4; ++i) av[i] = As[ty * 4 + i][kk];
#pragma unroll
            for (int j = 0; j < 4; ++j) bv[j] = WsT[kk][tx * 4 + j];
#pragma unroll
            for (int i = 0; i < 4; ++i)
#pragma unroll
                for (int j = 0; j < 4; ++j)
                    acc[i][j] = fmaf(av[i], bv[j], acc[i][j]);
        }
    }

#pragma unroll
    for (int i = 0; i < 4; ++i) {
        f32x4 v = { acc[i][0], acc[i][1], acc[i][2], acc[i][3] };
        *(f32x4*)&fg[(size_t)(m0 + ty * 4 + i) * 640 + n0 + tx * 4] = v;
    }
}

// ---------------------------------------------------------------------------
// Kernel 2: W_out fp32 [1024][640] -> fp16, TILED to the joint kernel's LDS
// image: elem offset = seg*10240 + kc*512 + L*8 + j, seg = n>>4, kc = k>>5,
// L = (n&15) + 16*((k>>3)&3).
// ---------------------------------------------------------------------------
__global__ __launch_bounds__(256) void wconv_kernel(
    const float* __restrict__ W, _Float16* __restrict__ Wh)
{
    const int tid = blockIdx.x * 256 + threadIdx.x;    // 81920 = 1024*80
    const int n   = tid / 80;
    const int c   = tid % 80;                          // k-chunk of 8
    f32x4 a = *(const f32x4*)(W + (size_t)n * 640 + c * 8);
    f32x4 b = *(const f32x4*)(W + (size_t)n * 640 + c * 8 + 4);
    f16x8 h;
#pragma unroll
    for (int j = 0; j < 4; ++j) { h[j] = (_Float16)a[j]; h[4 + j] = (_Float16)b[j]; }
    const int seg = n >> 4;
    const int kc  = c >> 2;
    const int L   = (n & 15) + 16 * (c & 3);
    *(f16x8*)(Wh + (size_t)seg * 10240 + kc * 512 + L * 8) = h;
}

// ---------------------------------------------------------------------------
// Kernel 3: fused tanh + big GEMM, two N-passes with interleaved stores.
// ---------------------------------------------------------------------------
__global__ __launch_bounds__(512, 2) void joint_kernel(
    const float* __restrict__ fg, const _Float16* __restrict__ Wh,
    const float* __restrict__ bias, float* __restrict__ out)
{
    __shared__ _Float16 Ash0[8 * 1040];     // 16.6 KB: 8 k-chunk regions
    __shared__ _Float16 Ash1[8 * 1040];
    __shared__ _Float16 Bsh0[2 * 8192];     // 32 KB: [half][seg16][512]
    __shared__ _Float16 Bsh1[2 * 8192];

    const int bid = blockIdx.x;             // 2048
    const int pp  = bid >> 1;               // 1024 m-tiles
    const int mt  = (pp & 7) * 128 + (pp >> 3);   // XCD-chunked (bijective)
    const int nt  = bid & 1;
    const int m0  = mt << 7;

    const int t    = threadIdx.x;
    const int lane = t & 63;
    const int wid  = t >> 6;
    const int wm   = wid & 1;               // m half (64 rows)
    const int wn   = wid >> 1;              // n quarter within pass (64 cols)
    const int lr   = lane & 15;
    const int lk   = lane >> 4;

    // stage-A mapping: 4 threads per row, 16 k each (chunks q and q+4)
    const int r  = t >> 2;                  // 0..127
    const int q  = t & 3;
    const int m  = m0 + r;
    const float* grow = fg + (size_t)(2048 + ((m >> 14) << 6) + (m & 63)) * 640;
    const float* frow = fg + (size_t)(m >> 6) * 640;

    // ---- loop-invariant LDS offsets (f16 elems) ----
    int aoff[4];
#pragma unroll
    for (int mf = 0; mf < 4; ++mf)
        aoff[mf] = lk * 1040 + (wm * 64 + mf * 16 + lr) * 8;
    int boff[4];
#pragma unroll
    for (int nf = 0; nf < 4; ++nf)
        boff[nf] = (wn * 4 + nf) * 512 + lane * 8;   // identity, zero conflict
    const int awoff = q * 1040 + r * 8;

    // gll bases per pass: segs = nt*32 + p*16 + wid*2 + {0,1}
    const _Float16* gbase0 = Wh + (size_t)(nt * 32 + wid * 2) * 10240 + lane * 8;
    const _Float16* gbase1 = gbase0 + (size_t)16 * 10240;
    const int gd0 = (wid * 2) * 512;        // + half*8192, + i*512

    // bias
    float bv0[4], bv1[4];
#pragma unroll
    for (int nf = 0; nf < 4; ++nf) {
        bv0[nf] = bias[nt * 512 +       wn * 64 + nf * 16 + lr];
        bv1[nf] = bias[nt * 512 + 256 + wn * 64 + nf * 16 + lr];
    }

    f32x4 acc0[4][4], acc1[4][4];
#pragma unroll
    for (int i = 0; i < 4; ++i)
#pragma unroll
        for (int j = 0; j < 4; ++j) {
            acc0[i][j] = (f32x4){0.f, 0.f, 0.f, 0.f};
            acc1[i][j] = (f32x4){0.f, 0.f, 0.f, 0.f};
        }

// ---- stage helpers ----
#define STAGE_B(GB, NB, KN)                                                    \
        _Pragma("unroll")                                                      \
        for (int i_ = 0; i_ < 2; ++i_)                                         \
            _Pragma("unroll")                                                  \
            for (int h_ = 0; h_ < 2; ++h_)                                     \
                gll16((GB) + (size_t)i_ * 10240 + (KN) * 16 + h_ * 512,        \
                      &(NB)[h_ * 8192 + gd0 + i_ * 512]);

#define STAGE_A(NA, KN)                                                        \
    {                                                                          \
        f32x4 fa = *(const f32x4*)(frow + (KN) + q * 8);                       \
        f32x4 fb = *(const f32x4*)(frow + (KN) + q * 8 + 4);                   \
        f32x4 fc = *(const f32x4*)(frow + (KN) + 32 + q * 8);                  \
        f32x4 fd = *(const f32x4*)(frow + (KN) + 32 + q * 8 + 4);              \
        f32x4 ga = *(const f32x4*)(grow + (KN) + q * 8);                       \
        f32x4 gb = *(const f32x4*)(grow + (KN) + q * 8 + 4);                   \
        f32x4 gc = *(const f32x4*)(grow + (KN) + 32 + q * 8);                  \
        f32x4 gd = *(const f32x4*)(grow + (KN) + 32 + q * 8 + 4);              \
        f16x8 h0, h1;                                                          \
        _Pragma("unroll")                                                      \
        for (int j = 0; j < 4; ++j) {                                          \
            h0[j]     = (_Float16)fast_tanh(fa[j] + ga[j]);                    \
            h0[4 + j] = (_Float16)fast_tanh(fb[j] + gb[j]);                    \
            h1[j]     = (_Float16)fast_tanh(fc[j] + gc[j]);                    \
            h1[4 + j] = (_Float16)fast_tanh(fd[j] + gd[j]);                    \
        }                                                                      \
        *(f16x8*)&(NA)[awoff]            = h0;                                 \
        *(f16x8*)&(NA)[awoff + 4 * 1040] = h1;                                 \
    }

// ---- full iteration: compute K0 from (CA,CB), stage K0+64 into (NA,NB).
// STC >= 0: store chunk STC of acc0 (pass-0 C) -- 8 dwords/thread.
#define JITER_FULL(K0, CA, CB, NA, NB, ACC, GB, STC)                           \
    {                                                                          \
        const int kn_ = (K0) + 64;                                             \
        /* f/g for next tile FIRST (in-order vmcnt: tanh waits only these) */  \
        f32x4 fa = *(const f32x4*)(frow + kn_ + q * 8);                        \
        f32x4 fb = *(const f32x4*)(frow + kn_ + q * 8 + 4);                    \
        f32x4 fc = *(const f32x4*)(frow + kn_ + 32 + q * 8);                   \
        f32x4 fd = *(const f32x4*)(frow + kn_ + 32 + q * 8 + 4);               \
        f32x4 ga = *(const f32x4*)(grow + kn_ + q * 8);                        \
        f32x4 gb = *(const f32x4*)(grow + kn_ + q * 8 + 4);                    \
        f32x4 gc = *(const f32x4*)(grow + kn_ + 32 + q * 8);                   \
        f32x4 gd = *(const f32x4*)(grow + kn_ + 32 + q * 8 + 4);               \
        STAGE_B(GB, NB, kn_)                                                   \
        f16x8 af[4], bf[4];                                                    \
        _Pragma("unroll")                                                      \
        for (int mf = 0; mf < 4; ++mf)                                         \
            af[mf] = *(const f16x8*)&(CA)[aoff[mf]];                           \
        _Pragma("unroll")                                                      \
        for (int nf = 0; nf < 4; ++nf)                                         \
            bf[nf] = *(const f16x8*)&(CB)[boff[nf]];                           \
        f16x8 h0, h1;                                                          \
        _Pragma("unroll")                                                      \
        for (int j = 0; j < 4; ++j) {                                          \
            h0[j]     = (_Float16)fast_tanh(fa[j] + ga[j]);                    \
            h0[4 + j] = (_Float16)fast_tanh(fb[j] + gb[j]);                    \
            h1[j]     = (_Float16)fast_tanh(fc[j] + gc[j]);                    \
            h1[4 + j] = (_Float16)fast_tanh(fd[j] + gd[j]);                    \
        }                                                                      \
        __builtin_amdgcn_s_setprio(1);                                         \
        _Pragma("unroll")                                                      \
        for (int mf = 0; mf < 4; ++mf)                                         \
            _Pragma("unroll")                                                  \
            for (int nf = 0; nf < 4; ++nf)                                     \
                ACC[mf][nf] = __builtin_amdgcn_mfma_f32_16x16x32_f16(          \
                    af[mf], bf[nf], ACC[mf][nf], 0, 0, 0);                     \
        __builtin_amdgcn_s_setprio(0);                                         \
        _Pragma("unroll")                                                      \
        for (int mf = 0; mf < 4; ++mf)                                         \
            af[mf] = *(const f16x8*)&(CA)[aoff[mf] + 4 * 1040];                \
        _Pragma("unroll")                                                      \
        for (int nf = 0; nf < 4; ++nf)                                         \
            bf[nf] = *(const f16x8*)&(CB)[boff[nf] + 8192];                    \
        __builtin_amdgcn_s_setprio(1);                                         \
        _Pragma("unroll")                                                      \
        for (int mf = 0; mf < 4; ++mf)                                         \
            _Pragma("unroll")                                                  \
            for (int nf = 0; nf < 4; ++nf)                                     \
                ACC[mf][nf] = __builtin_amdgcn_mfma_f32_16x16x32_f16(          \
                    af[mf], bf[nf], ACC[mf][nf], 0, 0, 0);                     \
        __builtin_amdgcn_s_setprio(0);                                         \
        if ((STC) >= 0) {                                                      \
            const int smf = (STC) >> 1;                                        \
            const int sr0 = ((STC) & 1) << 1;                                  \
            _Pragma("unroll")                                                  \
            for (int rr2 = 0; rr2 < 2; ++rr2) {                                \
                const int row = m0 + wm * 64 + smf * 16 + lk * 4 + sr0 + rr2;  \
                float* orow = out + (size_t)row * 1024 + nt * 512 + wn * 64;   \
                _Pragma("unroll")                                              \
                for (int nf = 0; nf < 4; ++nf)                                 \
                    orow[nf * 16 + lr] = acc0[smf][nf][sr0 + rr2] + bv0[nf];   \
            }                                                                  \
        }                                                                      \
        *(f16x8*)&(NA)[awoff]            = h0;                                 \
        *(f16x8*)&(NA)[awoff + 4 * 1040] = h1;                                 \
        __syncthreads();                                                       \
    }

#define JITER_LAST(CA, CB, ACC)                                                \
    {                                                                          \
        f16x8 af[4], bf[4];                                                    \
        _Pragma("unroll")                                                      \
        for (int mf = 0; mf < 4; ++mf)                                         \
            af[mf] = *(const f16x8*)&(CA)[aoff[mf]];                           \
        _Pragma("unroll")                                                      \
        for (int nf = 0; nf < 4; ++nf)                                         \
            bf[nf] = *(const f16x8*)&(CB)[boff[nf]];                           \
        __builtin_amdgcn_s_setprio(1);                                         \
        _Pragma("unroll")                                                      \
        for (int mf = 0; mf < 4; ++mf)                                         \
            _Pragma("unroll")                                                  \
            for (int nf = 0; nf < 4; ++nf)                                     \
                ACC[mf][nf] = __builtin_amdgcn_mfma_f32_16x16x32_f16(          \
                    af[mf], bf[nf], ACC[mf][nf], 0, 0, 0);                     \
        __builtin_amdgcn_s_setprio(0);                                         \
        _Pragma("unroll")                                                      \
        for (int mf = 0; mf < 4; ++mf)                                         \
            af[mf] = *(const f16x8*)&(CA)[aoff[mf] + 4 * 1040];                \
        _Pragma("unroll")                                                      \
        for (int nf = 0; nf < 4; ++nf)                                         \
            bf[nf] = *(const f16x8*)&(CB)[boff[nf] + 8192];                    \
        __builtin_amdgcn_s_setprio(1);                                         \
        _Pragma("unroll")                                                      \
        for (int mf = 0; mf < 4; ++mf)                                         \
            _Pragma("unroll")                                                  \
            for (int nf = 0; nf < 4; ++nf)                                     \
                ACC[mf][nf] = __builtin_amdgcn_mfma_f32_16x16x32_f16(          \
                    af[mf], bf[nf], ACC[mf][nf], 0, 0, 0);                     \
        __builtin_amdgcn_s_setprio(0);                                         \
    }

    // ================= PASS 0 (cols nt*512 .. +255) =================
    {
        STAGE_B(gbase0, Bsh0, 0)
        STAGE_A(Ash0, 0)
        __syncthreads();
    }
#pragma unroll
    for (int kc = 0; kc < 8; kc += 2) {
        JITER_FULL(kc * 64,      Ash0, Bsh0, Ash1, Bsh1, acc0, gbase0, -1);
        JITER_FULL(kc * 64 + 64, Ash1, Bsh1, Ash0, Bsh0, acc0, gbase0, -1);
    }
    JITER_FULL(512, Ash0, Bsh0, Ash1, Bsh1, acc0, gbase0, -1);
    JITER_LAST(Ash1, Bsh1, acc0);

    // ================= PASS 1 (cols nt*512+256 .. +511) =============
    // interleaves acc0's stores (chunks 0..7) into its first 8 iterations
    {
        STAGE_B(gbase1, Bsh0, 0)
        STAGE_A(Ash0, 0)
        __syncthreads();
    }
#pragma unroll
    for (int kc = 0; kc < 8; kc += 2) {
        JITER_FULL(kc * 64,      Ash0, Bsh0, Ash1, Bsh1, acc1, gbase1, kc);
        JITER_FULL(kc * 64 + 64, Ash1, Bsh1, Ash0, Bsh0, acc1, gbase1, kc + 1);
    }
    JITER_FULL(512, Ash0, Bsh0, Ash1, Bsh1, acc1, gbase1, -1);
    JITER_LAST(Ash1, Bsh1, acc1);

#undef JITER_FULL
#undef JITER_LAST
#undef STAGE_A
#undef STAGE_B

    // ---- final epilogue: acc1 + bias, cached stores ----
#pragma unroll
    for (int mf = 0; mf < 4; ++mf) {
#pragma unroll
        for (int rr = 0; rr < 4; ++rr) {
            const int row = m0 + wm * 64 + mf * 16 + lk * 4 + rr;
            float* orow = out + (size_t)row * 1024 + nt * 512 + 256 + wn * 64;
#pragma unroll
            for (int nf = 0; nf < 4; ++nf)
                orow[nf * 16 + lr] = acc1[mf][nf][rr] + bv1[nf];
        }
    }
}

// ---------------------------------------------------------------------------
extern "C" void kernel_launch(void* const* d_in, const int* in_sizes, int n_in,
                              void* d_out, int out_size, void* d_ws, size_t ws_size,
                              hipStream_t stream) {
    const float* enc   = (const float*)d_in[0];   // [8,256,512]
    const float* pred  = (const float*)d_in[1];   // [8,64,512]
    const float* Wenc  = (const float*)d_in[2];   // [640,512]
    const float* Wpred = (const float*)d_in[3];   // [640,512]
    const float* Wout  = (const float*)d_in[4];   // [1024,640]
    const float* bout  = (const float*)d_in[5];   // [1024]

    float*     fg = (float*)d_ws;                              // 2560*640 fp32
    _Float16*  Wh = (_Float16*)((char*)d_ws + 2560 * 640 * 4); // tiled 1.25MB

    fg_kernel<<<400, 256, 0, stream>>>(enc, pred, Wenc, Wpred, fg);
    wconv_kernel<<<320, 256, 0, stream>>>(Wout, Wh);
    joint_kernel<<<2048, 512, 0, stream>>>(fg, Wh, bout, (float*)d_out);
}